// Round 10
// baseline (790.924 us; speedup 1.0000x reference)
//
#include <hip/hip_runtime.h>
#include <hip/hip_bf16.h>

// ---------------------------------------------------------------------------
// Attention (B=4, S=4096, d_model=d_attn=2048), fp32 in/out, bf16 MFMA.
// R9: A/B test of intra-phase counted-lgkm GEMM body (BODY=2) on g_xgvot:
//     per phase, reads ordered [kk0-group, kk1-group]; barrier; lgkmcnt(6|2);
//     8 MFMA (kk0); lgkmcnt(0); 8 MFMA (kk1) -- LDS read tail drains UNDER
//     the first MFMA half instead of before it. Staging/barriers/vmcnt
//     identical to proven body (race-equivalent). g_small/g_qkt/g_pv keep
//     the proven body. Rest as R8 (exp-in-epilogue, RSI normalization,
//     merged xG+VOt, algebra: G=Wq^T Wk, Wvo=Wo Wv).
// Workspace: 370 MiB.
// ---------------------------------------------------------------------------

#define S_ 4096
#define DM_ 2048
#define DA_ 2048
#define NB_ 4

typedef __attribute__((ext_vector_type(8))) short short8;
typedef __attribute__((ext_vector_type(4))) float f32x4;
typedef __attribute__((ext_vector_type(8))) unsigned short ushort8;

__device__ __forceinline__ void gload_lds16(const void* g, void* l) {
  __builtin_amdgcn_global_load_lds(
      (const __attribute__((address_space(1))) void*)g,
      (__attribute__((address_space(3))) void*)l, 16, 0, 0);
}

__device__ __forceinline__ unsigned short f2bf(float f) {
  __hip_bfloat16 h = __float2bfloat16(f);
  return __builtin_bit_cast(unsigned short, h);
}

#define STAGE_A(par, h, kt)                                                    \
  {                                                                            \
    const __hip_bfloat16* s0 = Asrc + (size_t)((h)*128) * lda + (kt)*64;       \
    gload_lds16(s0, dstA + (par)*32768 + (h)*16384);                           \
    gload_lds16(s0 + (size_t)64 * lda, dstA + (par)*32768 + (h)*16384 + 8192); \
  }
#define STAGE_B(par, h, kt)                                                    \
  {                                                                            \
    const __hip_bfloat16* s0 = Bsrc + (size_t)((h)*128) * ldb + (kt)*64;       \
    gload_lds16(s0, dstB + (par)*32768 + (h)*16384);                           \
    gload_lds16(s0 + (size_t)64 * ldb, dstB + (par)*32768 + (h)*16384 + 8192); \
  }
#define LDA_FRAG(par, mi, i, kk) \
  (*(const short8*)(ldsAr + (par)*32768 + ((mi)*2 + (i)) * 2048 + (kk)*1024))
#define LDB_FRAG(par, j, kk) \
  (*(const short8*)(ldsBr + (par)*32768 + (j)*2048 + (kk)*1024))

#define MFMA_ON(mi, AF)                                                     \
  __builtin_amdgcn_s_setprio(1);                                            \
  _Pragma("unroll") for (int i = 0; i < 2; ++i)                             \
      _Pragma("unroll") for (int j = 0; j < 4; ++j)                         \
          _Pragma("unroll") for (int kk = 0; kk < 2; ++kk)                  \
              acc[(mi)*2 + i][j] = __builtin_amdgcn_mfma_f32_16x16x32_bf16( \
                  AF[i][kk], Bf[j][kk], acc[(mi)*2 + i][j], 0, 0, 0);       \
  __builtin_amdgcn_s_setprio(0);

// half-cluster: 8 MFMA at fixed kk
#define MFMA_HALF(mi, kk)                                                   \
  _Pragma("unroll") for (int i = 0; i < 2; ++i)                             \
      _Pragma("unroll") for (int j = 0; j < 4; ++j)                         \
          acc[(mi)*2 + i][j] = __builtin_amdgcn_mfma_f32_16x16x32_bf16(     \
              Af[i][kk], Bf[j][kk], acc[(mi)*2 + i][j], 0, 0, 0);

#define PHASE_SYNC_PRE                               \
  __builtin_amdgcn_s_barrier();                      \
  asm volatile("s_waitcnt lgkmcnt(0)" ::: "memory"); \
  __builtin_amdgcn_sched_barrier(0);

// proven 8-barrier body (R6-R8).
template <int PAR>
__device__ __forceinline__ void tile_body(
    int t, int NT, const __hip_bfloat16* __restrict__ Asrc,
    const __hip_bfloat16* __restrict__ Bsrc, int lda, int ldb, char* dstA,
    char* dstB, const char* ldsAr, const char* ldsBr, f32x4 (&acc)[8][4]) {
  const int tn = min(t + 1, NT - 1);
  const int tf = min(t + 2, NT - 1);
  short8 Bf[4][2], Af[2][2];

  // ph0
#pragma unroll
  for (int j = 0; j < 4; ++j)
#pragma unroll
    for (int kk = 0; kk < 2; ++kk) Bf[j][kk] = LDB_FRAG(PAR, j, kk);
#pragma unroll
  for (int i = 0; i < 2; ++i)
#pragma unroll
    for (int kk = 0; kk < 2; ++kk) Af[i][kk] = LDA_FRAG(PAR, 0, i, kk);
  STAGE_A(PAR ^ 1, 0, tn);
  PHASE_SYNC_PRE
  MFMA_ON(0, Af)
  __builtin_amdgcn_s_barrier();

  // ph1
#pragma unroll
  for (int i = 0; i < 2; ++i)
#pragma unroll
    for (int kk = 0; kk < 2; ++kk) Af[i][kk] = LDA_FRAG(PAR, 1, i, kk);
  STAGE_A(PAR ^ 1, 1, tn);
  PHASE_SYNC_PRE
  MFMA_ON(1, Af)
  __builtin_amdgcn_s_barrier();

  // ph2
#pragma unroll
  for (int i = 0; i < 2; ++i)
#pragma unroll
    for (int kk = 0; kk < 2; ++kk) Af[i][kk] = LDA_FRAG(PAR, 2, i, kk);
  STAGE_B(PAR, 0, tf);
  PHASE_SYNC_PRE
  MFMA_ON(2, Af)
  __builtin_amdgcn_s_barrier();

  // ph3
#pragma unroll
  for (int i = 0; i < 2; ++i)
#pragma unroll
    for (int kk = 0; kk < 2; ++kk) Af[i][kk] = LDA_FRAG(PAR, 3, i, kk);
  STAGE_B(PAR, 1, tf);
  PHASE_SYNC_PRE
  MFMA_ON(3, Af)
  asm volatile("s_waitcnt vmcnt(4)" ::: "memory");
  __builtin_amdgcn_s_barrier();
  __builtin_amdgcn_sched_barrier(0);
}

// BODY=2: intra-phase counted-lgkm variant. Same staging/barriers/vmcnt as
// tile_body (race-equivalent); only the lgkm waits + read grouping differ.
template <int PAR>
__device__ __forceinline__ void tile_body3(
    int t, int NT, const __hip_bfloat16* __restrict__ Asrc,
    const __hip_bfloat16* __restrict__ Bsrc, int lda, int ldb, char* dstA,
    char* dstB, const char* ldsAr, const char* ldsBr, f32x4 (&acc)[8][4]) {
  const int tn = min(t + 1, NT - 1);
  const int tf = min(t + 2, NT - 1);
  short8 Bf[4][2], Af[2][2];

  // ph0 (mi=0): 12 reads ordered [B kk0 x4, A kk0 x2 | B kk1 x4, A kk1 x2]
#pragma unroll
  for (int j = 0; j < 4; ++j) Bf[j][0] = LDB_FRAG(PAR, j, 0);
#pragma unroll
  for (int i = 0; i < 2; ++i) Af[i][0] = LDA_FRAG(PAR, 0, i, 0);
  __builtin_amdgcn_sched_barrier(0);  // pin kk0-group before kk1-group
#pragma unroll
  for (int j = 0; j < 4; ++j) Bf[j][1] = LDB_FRAG(PAR, j, 1);
#pragma unroll
  for (int i = 0; i < 2; ++i) Af[i][1] = LDA_FRAG(PAR, 0, i, 1);
  STAGE_A(PAR ^ 1, 0, tn);
  __builtin_amdgcn_sched_barrier(0);
  __builtin_amdgcn_s_barrier();
  asm volatile("s_waitcnt lgkmcnt(6)" ::: "memory");  // kk0 operands landed
  __builtin_amdgcn_sched_barrier(0);
  __builtin_amdgcn_s_setprio(1);
  MFMA_HALF(0, 0)
  asm volatile("s_waitcnt lgkmcnt(0)" ::: "memory");  // kk1 drained under kk0
  __builtin_amdgcn_sched_barrier(0);
  MFMA_HALF(0, 1)
  __builtin_amdgcn_s_setprio(0);
  __builtin_amdgcn_s_barrier();
  __builtin_amdgcn_sched_barrier(0);

#define PHASE3(mi, STG, LASTV)                                          \
  _Pragma("unroll") for (int i = 0; i < 2; ++i)                         \
      Af[i][0] = LDA_FRAG(PAR, mi, i, 0);                               \
  __builtin_amdgcn_sched_barrier(0);                                    \
  _Pragma("unroll") for (int i = 0; i < 2; ++i)                         \
      Af[i][1] = LDA_FRAG(PAR, mi, i, 1);                               \
  STG;                                                                  \
  __builtin_amdgcn_sched_barrier(0);                                    \
  __builtin_amdgcn_s_barrier();                                         \
  asm volatile("s_waitcnt lgkmcnt(2)" ::: "memory");                    \
  __builtin_amdgcn_sched_barrier(0);                                    \
  __builtin_amdgcn_s_setprio(1);                                        \
  MFMA_HALF(mi, 0)                                                      \
  asm volatile("s_waitcnt lgkmcnt(0)" ::: "memory");                    \
  __builtin_amdgcn_sched_barrier(0);                                    \
  MFMA_HALF(mi, 1)                                                      \
  __builtin_amdgcn_s_setprio(0);                                        \
  if (LASTV) asm volatile("s_waitcnt vmcnt(4)" ::: "memory");           \
  __builtin_amdgcn_s_barrier();                                         \
  __builtin_amdgcn_sched_barrier(0);

  PHASE3(1, STAGE_A(PAR ^ 1, 1, tn), 0)
  PHASE3(2, STAGE_B(PAR, 0, tf), 0)
  PHASE3(3, STAGE_B(PAR, 1, tf), 1)
#undef PHASE3
}

// C[M,N] = A[M,K] * B[N,K]^T ; 256x256 tile, BK=64, 8 waves, 16x16x32 MFMA.
// EPI 0: C bf16
// EPI 3: C bf16 = exp(acc*scale); aux = PS[NB][16][4096] row partial sums
// EPI 4: C fp32 = acc * aux(RSI)[row] + bias[col]
// BODY 0: proven ; BODY 2: intra-phase counted-lgkm
template <int EPI, int BODY>
__device__ __forceinline__ void gemm8_body(
    int wgin, int nwg, const __hip_bfloat16* __restrict__ A,
    const __hip_bfloat16* __restrict__ Bm, void* __restrict__ Cv,
    const float* __restrict__ bias, float* __restrict__ aux, int N, int K,
    int lda, int ldb, int ldc, float scale, long strideA, long strideB,
    long strideC) {
  __shared__ alignas(16) char lds[131072];
  const int tid = threadIdx.x;
  const int lane = tid & 63;
  const int w = tid >> 6;
  const int wr = w >> 2, wc = w & 3;

  // XCD-contiguous transform + 4x4 supertile decode (L2 locality).
  int wg = (wgin & 7) * (nwg >> 3) + (wgin >> 3);
  const int nbn = N >> 8;
  const int nstx = nbn >> 2;
  const int st = wg >> 4;
  const int bm = (st / nstx) * 4 + ((wg >> 2) & 3);
  const int bn = (st % nstx) * 4 + (wg & 3);

  A += (long)blockIdx.y * strideA;
  Bm += (long)blockIdx.y * strideB;

  // staging source coords (pre-swizzled column: involution of read XOR)
  const int R = ((w >> 1) << 4) + (lane >> 2);
  const int Cc = ((w & 1) << 5) + (((lane & 3) << 3) ^ ((lane & 32) >> 1));
  const __hip_bfloat16* Asrc = A + (size_t)(bm * 256 + R) * lda + Cc;
  const __hip_bfloat16* Bsrc = Bm + (size_t)(bn * 256 + R) * ldb + Cc;
  char* dstA = lds + w * 1024 + lane * 16;
  char* dstB = dstA + 65536;

  // read-side swizzled base offsets (verified conflict-free)
  const int fr = lane & 15;
  const int fk2 = (lane >> 4) << 4;
  const int rby = fr * 64 + (fk2 ^ ((fr & 8) << 2));
  const char* ldsAr = lds + wr * 16384 + rby;
  const char* ldsBr = lds + 65536 + (wc >> 1) * 16384 + (wc & 1) * 8192 + rby;

  const int NT = K >> 6;
  f32x4 acc[8][4] = {};

  // prologue: T0 all 4 halves -> par0; T1 B halves -> par1; vmcnt(4) keeps
  // T1's B (4 loads) in flight = steady state.
  STAGE_A(0, 0, 0)
  STAGE_A(0, 1, 0)
  STAGE_B(0, 0, 0)
  STAGE_B(0, 1, 0)
  STAGE_B(1, 0, 1)
  STAGE_B(1, 1, 1)
  asm volatile("s_waitcnt vmcnt(4)" ::: "memory");
  __builtin_amdgcn_s_barrier();
  __builtin_amdgcn_sched_barrier(0);

  for (int t = 0; t < NT; t += 2) {
    if (BODY == 0) {
      tile_body<0>(t, NT, Asrc, Bsrc, lda, ldb, dstA, dstB, ldsAr, ldsBr, acc);
      tile_body<1>(t + 1, NT, Asrc, Bsrc, lda, ldb, dstA, dstB, ldsAr, ldsBr,
                   acc);
    } else {
      tile_body3<0>(t, NT, Asrc, Bsrc, lda, ldb, dstA, dstB, ldsAr, ldsBr, acc);
      tile_body3<1>(t + 1, NT, Asrc, Bsrc, lda, ldb, dstA, dstB, ldsAr, ldsBr,
                    acc);
    }
  }
  asm volatile("s_waitcnt vmcnt(0)" ::: "memory");

  // epilogue: C/D layout col=lane&15, row=(lane>>4)*4+reg  [verified m89/m91]
  float* Cf = (float*)Cv;
  __hip_bfloat16* Cb = (__hip_bfloat16*)Cv;
  const size_t cbase = (size_t)blockIdx.y * (size_t)strideC;
  const int r0 = bm * 256 + wr * 128 + ((lane >> 4) << 2);
  const int c0 = bn * 256 + wc * 64 + fr;

  if (EPI == 3) {
    __syncthreads();
    float* rpart = (float*)lds;  // [4 wc][256 blockrow]
#pragma unroll
    for (int mi = 0; mi < 4; ++mi) {
      float pr[8] = {};
#pragma unroll
      for (int i = 0; i < 2; ++i)
#pragma unroll
        for (int j = 0; j < 4; ++j) {
          const int row = r0 + mi * 32 + i * 16;
          const int col = c0 + j * 16;
#pragma unroll
          for (int r = 0; r < 4; ++r) {
            const float p = __expf(acc[mi * 2 + i][j][r] * scale);
            Cb[cbase + (size_t)(row + r) * ldc + col] = __float2bfloat16(p);
            pr[i * 4 + r] += p;
          }
        }
#pragma unroll
      for (int k = 0; k < 8; ++k) {
#pragma unroll
        for (int m = 1; m <= 8; m <<= 1) pr[k] += __shfl_xor(pr[k], m);
      }
      if (fr == 0) {
#pragma unroll
        for (int i = 0; i < 2; ++i)
#pragma unroll
          for (int r = 0; r < 4; ++r)
            rpart[wc * 256 + wr * 128 + mi * 32 + i * 16 +
                  ((lane >> 4) << 2) + r] = pr[i * 4 + r];
      }
    }
    __syncthreads();
    if (tid < 256) {
      const float s = rpart[tid] + rpart[256 + tid] + rpart[512 + tid] +
                      rpart[768 + tid];
      aux[(size_t)blockIdx.y * 65536 + (size_t)bn * 4096 + bm * 256 + tid] = s;
    }
    return;
  }

#pragma unroll
  for (int mi = 0; mi < 4; ++mi)
#pragma unroll
    for (int i = 0; i < 2; ++i) {
      float rsv[4];
      if (EPI == 4) {
#pragma unroll
        for (int r = 0; r < 4; ++r)
          rsv[r] = aux[(size_t)blockIdx.y * 4096 + r0 + mi * 32 + i * 16 + r];
      }
#pragma unroll
      for (int j = 0; j < 4; ++j) {
        const int row = r0 + mi * 32 + i * 16;
        const int col = c0 + j * 16;
#pragma unroll
        for (int r = 0; r < 4; ++r) {
          const float v = acc[mi * 2 + i][j][r];
          if (EPI == 0)
            Cb[cbase + (size_t)(row + r) * ldc + col] = __float2bfloat16(v);
          else  // EPI == 4
            Cf[cbase + (size_t)(row + r) * ldc + col] = v * rsv[r] + bias[col];
        }
      }
    }
}

#define GEMM_WRAP(NAME, EPI, BODY)                                             \
  __global__ __launch_bounds__(512, 1) void NAME(                              \
      const __hip_bfloat16* __restrict__ A,                                    \
      const __hip_bfloat16* __restrict__ Bm, void* __restrict__ Cv,            \
      const float* __restrict__ bias, float* __restrict__ aux, int N, int K,   \
      int lda, int ldb, int ldc, float scale, long strideA, long strideB,      \
      long strideC) {                                                          \
    gemm8_body<EPI, BODY>(blockIdx.x, gridDim.x, A, Bm, Cv, bias, aux, N, K,   \
                          lda, ldb, ldc, scale, strideA, strideB, strideC);    \
  }
GEMM_WRAP(g_small, 0, 0)  // y=2: {Gt, Wvo} 2048^3 pair        [proven]
GEMM_WRAP(g_qkt, 3, 0)    // P_b = exp(...), + PS row sums     [proven]
GEMM_WRAP(g_pv, 4, 0)     // out_b = acc * RSI + bo            [proven]

// merged xG + VOt dispatch (independent GEMMs, one launch)  [BODY=2 A/B]
__global__ __launch_bounds__(512, 1) void g_xgvot(
    const __hip_bfloat16* __restrict__ Xb, const __hip_bfloat16* __restrict__ Gt,
    __hip_bfloat16* __restrict__ xG, const __hip_bfloat16* __restrict__ Wvo,
    __hip_bfloat16* __restrict__ VOt) {
  const int b = blockIdx.x;
  const __hip_bfloat16 *Ap, *Bp;
  __hip_bfloat16* Cp;
  int wg, nwg, N, ldc;
  if (b < 512) {  // xG = bt(Xb, Gt): [16384, 2048], K=2048
    Ap = Xb; Bp = Gt; Cp = xG;
    wg = b; nwg = 512; N = 2048; ldc = 2048;
  } else {        // VOt_y = bt(Wvo, Xb_y): [2048, 4096] x4, K=2048
    const int vb = b - 512;
    const int y = vb >> 7;
    Ap = Wvo; Bp = Xb + (size_t)y * S_ * DM_; Cp = VOt + (size_t)y * DA_ * S_;
    wg = vb & 127; nwg = 128; N = 4096; ldc = 4096;
  }
  gemm8_body<0, 2>(wg, nwg, Ap, Bp, Cp, nullptr, nullptr, N, 2048, 2048, 2048,
                   ldc, 1.f, 0, 0, 0);
}

// RSI[y][row] = 1 / sum_cb PS[y][cb][row]   (16384 rows)
__global__ __launch_bounds__(256) void rs_inv(const float* __restrict__ PS,
                                              float* __restrict__ RSI) {
  const int t = blockIdx.x * 256 + threadIdx.x;
  const int y = t >> 12;
  const int row = t & 4095;
  float s = 0.f;
#pragma unroll
  for (int cb = 0; cb < 16; ++cb) s += PS[(size_t)y * 65536 + cb * 4096 + row];
  RSI[t] = 1.0f / s;
}

// transpose-cast one 64x64 tile of a 2048x2048 f32 matrix -> bf16 transposed
__device__ __forceinline__ void tcast64(const float* __restrict__ src,
                                        __hip_bfloat16* __restrict__ dst,
                                        int tile) {
  __shared__ __hip_bfloat16 lt[64][65];
  const int ti = tile >> 5;
  const int tj = tile & 31;
  const int t = threadIdx.x;
  const int r = t >> 4;
  const int c4 = (t & 15) * 4;
#pragma unroll
  for (int rr = 0; rr < 4; ++rr) {
    const int row = ti * 64 + rr * 16 + r;
    const f32x4 v = *(const f32x4*)(src + (size_t)row * 2048 + tj * 64 + c4);
#pragma unroll
    for (int k = 0; k < 4; ++k)
      lt[c4 + k][rr * 16 + r] = __float2bfloat16(v[k]);
  }
  __syncthreads();
  const int a = t >> 2;
  const int b16 = (t & 3) * 16;
  ushort8* dp = (ushort8*)(dst + (size_t)(tj * 64 + a) * 2048 + ti * 64 + b16);
  const unsigned short* lp = (const unsigned short*)&lt[a][b16];
  ushort8 o0, o1;
#pragma unroll
  for (int k = 0; k < 8; ++k) {
    o0[k] = lp[k];
    o1[k] = lp[8 + k];
  }
  dp[0] = o0;
  dp[1] = o1;
}

// fused cast: x plain (16384), Wo plain (2048), Wq/Wk/Wv transpose (1024 ea)
__global__ __launch_bounds__(256) void cast_all(
    const float* __restrict__ x, const float* __restrict__ wq,
    const float* __restrict__ wk, const float* __restrict__ wv,
    const float* __restrict__ wo, __hip_bfloat16* __restrict__ xb,
    __hip_bfloat16* __restrict__ wqt, __hip_bfloat16* __restrict__ wkt,
    __hip_bfloat16* __restrict__ wvt, __hip_bfloat16* __restrict__ wob) {
  const int b = blockIdx.x;
  if (b >= 18432) {
    if (b < 19456) tcast64(wq, wqt, b - 18432);
    else if (b < 20480) tcast64(wk, wkt, b - 19456);
    else tcast64(wv, wvt, b - 20480);
    return;
  }
  const float* src;
  __hip_bfloat16* dst;
  long base;
  if (b < 16384) {
    src = x; dst = xb; base = (long)b;
  } else {
    src = wo; dst = wob; base = (long)(b - 16384);
  }
  const long i = (base * 256 + threadIdx.x) * 8;
  const f32x4 a = *(const f32x4*)(src + i);
  const f32x4 c = *(const f32x4*)(src + i + 4);
  ushort8 o;
#pragma unroll
  for (int j = 0; j < 4; ++j) o[j] = f2bf(a[j]);
#pragma unroll
  for (int j = 0; j < 4; ++j) o[4 + j] = f2bf(c[j]);
  *(ushort8*)(dst + i) = o;
}

extern "C" void kernel_launch(void* const* d_in, const int* in_sizes, int n_in,
                              void* d_out, int out_size, void* d_ws,
                              size_t ws_size, hipStream_t stream) {
  (void)in_sizes; (void)n_in; (void)out_size; (void)ws_size;
  const float* x = (const float*)d_in[0];
  const float* Wq = (const float*)d_in[1];
  const float* Wk = (const float*)d_in[2];
  const float* Wv = (const float*)d_in[3];
  const float* Wo = (const float*)d_in[4];
  const float* bo = (const float*)d_in[5];
  float* out = (float*)d_out;

  const long MB = 1ll << 20;
  char* ws = (char*)d_ws;  // 370 MiB
  __hip_bfloat16* Xb  = (__hip_bfloat16*)(ws);             // 64 MiB
  __hip_bfloat16* xG  = (__hip_bfloat16*)(ws + 64 * MB);   // 64 MiB
  __hip_bfloat16* VOt = (__hip_bfloat16*)(ws + 128 * MB);  // 64 MiB
  __hip_bfloat16* WkT = (__hip_bfloat16*)(ws + 192 * MB);  // 8 MiB  [smallA y0]
  __hip_bfloat16* Wob = (__hip_bfloat16*)(ws + 200 * MB);  // 8 MiB  [smallA y1]
  __hip_bfloat16* WqT = (__hip_bfloat16*)(ws + 208 * MB);  // 8 MiB  [smallB y0]
  __hip_bfloat16* WvT = (__hip_bfloat16*)(ws + 216 * MB);  // 8 MiB  [smallB y1]
  __hip_bfloat16* Gt  = (__hip_bfloat16*)(ws + 224 * MB);  // 8 MiB  [smallC y0]
  __hip_bfloat16* Wvo = (__hip_bfloat16*)(ws + 232 * MB);  // 8 MiB  [smallC y1]
  char* LgP           = ws + 240 * MB;                     // 128 MiB (P bf16)
  float* PS           = (float*)(ws + 368 * MB);           // 1 MiB
  float* RSI          = (float*)(ws + 369 * MB);           // 64 KiB

  const long WSTRIDE = 8 * MB / 2;  // elements between y=0 / y=1 operands

  cast_all<<<dim3(21504), dim3(256), 0, stream>>>(x, Wq, Wk, Wv, Wo, Xb, WqT,
                                                  WkT, WvT, Wob);

  // {Gt, Wvo} = { bt(WkT,WqT), bt(Wob,WvT) } : one y=2 dispatch, 2048^3 each
  g_small<<<dim3(64, 2), dim3(512), 0, stream>>>(
      WkT, WqT, Gt, nullptr, nullptr, 2048, 2048, 2048, 2048, 2048, 1.f,
      WSTRIDE, WSTRIDE, WSTRIDE);
  // xG = bt(Xb, Gt) and VOt_b = bt(Wvo, Xb_b) merged (independent)
  g_xgvot<<<dim3(1024, 1), dim3(512), 0, stream>>>(Xb, Gt, xG, Wvo, VOt);

  const float scale = 0.022097086912079608f;  // 1/sqrt(d_model=2048)
  // P_b = exp(bt(xG_b, Xb_b)*scale) -> bf16 [4096,4096] x4 ; PS row sums
  g_qkt<<<dim3(256, NB_), dim3(512), 0, stream>>>(
      xG, Xb, LgP, nullptr, PS, 4096, 2048, 2048, 2048, 4096, scale,
      (long)S_ * DA_, (long)S_ * DM_, (long)S_ * S_);
  rs_inv<<<dim3(64), dim3(256), 0, stream>>>(PS, RSI);
  // out_b = bt(P_b, VOt_b) * RSI + bo -> fp32 [4096, 2048] x4, K=4096
  g_pv<<<dim3(128, NB_), dim3(512), 0, stream>>>(
      (const __hip_bfloat16*)LgP, VOt, out, bo, RSI, 2048, 4096, 4096, 4096,
      2048, 1.f, (long)S_ * S_, (long)DA_ * S_, (long)S_ * DM_);
}

// Round 11
// 780.847 us; speedup vs baseline: 1.0129x; 1.0129x over previous
//
#include <hip/hip_runtime.h>
#include <hip/hip_bf16.h>

// ---------------------------------------------------------------------------
// Attention (B=4, S=4096, d_model=d_attn=2048), fp32 in/out, bf16 MFMA.
// R10: fringe elimination. (1) x-cast folded into the g_small dispatch
//      (GEMM blocks 0-63 x y=2 + 2048 x-cast blocks fill the idle half-GPU);
//      weights cast in a small preceding cast_w dispatch. (2) rs_inv fused
//      into g_pv (pre-staging PS reduction -> reg; post-loop LDS bounce).
//      K-loop frozen (6 schedule-variant nulls): proven 8-barrier body.
//      Algebra as R6-R9: Gt=bt(WkT,WqT), Wvo=bt(Wob,WvT), xG=bt(Xb,Gt),
//      VOt=bt(Wvo,Xb_b), P=exp(bt(xG_b,Xb_b)*scale) (+row sums PS),
//      out=bt(P_b,VOt_b)*RSI+bo.
// Workspace: 370 MiB.
// ---------------------------------------------------------------------------

#define S_ 4096
#define DM_ 2048
#define DA_ 2048
#define NB_ 4

typedef __attribute__((ext_vector_type(8))) short short8;
typedef __attribute__((ext_vector_type(4))) float f32x4;
typedef __attribute__((ext_vector_type(8))) unsigned short ushort8;

__device__ __forceinline__ void gload_lds16(const void* g, void* l) {
  __builtin_amdgcn_global_load_lds(
      (const __attribute__((address_space(1))) void*)g,
      (__attribute__((address_space(3))) void*)l, 16, 0, 0);
}

__device__ __forceinline__ unsigned short f2bf(float f) {
  __hip_bfloat16 h = __float2bfloat16(f);
  return __builtin_bit_cast(unsigned short, h);
}

#define STAGE_A(par, h, kt)                                                    \
  {                                                                            \
    const __hip_bfloat16* s0 = Asrc + (size_t)((h)*128) * lda + (kt)*64;       \
    gload_lds16(s0, dstA + (par)*32768 + (h)*16384);                           \
    gload_lds16(s0 + (size_t)64 * lda, dstA + (par)*32768 + (h)*16384 + 8192); \
  }
#define STAGE_B(par, h, kt)                                                    \
  {                                                                            \
    const __hip_bfloat16* s0 = Bsrc + (size_t)((h)*128) * ldb + (kt)*64;       \
    gload_lds16(s0, dstB + (par)*32768 + (h)*16384);                           \
    gload_lds16(s0 + (size_t)64 * ldb, dstB + (par)*32768 + (h)*16384 + 8192); \
  }
#define LDA_FRAG(par, mi, i, kk) \
  (*(const short8*)(ldsAr + (par)*32768 + ((mi)*2 + (i)) * 2048 + (kk)*1024))
#define LDB_FRAG(par, j, kk) \
  (*(const short8*)(ldsBr + (par)*32768 + (j)*2048 + (kk)*1024))

#define MFMA_ON(mi, AF)                                                     \
  __builtin_amdgcn_s_setprio(1);                                            \
  _Pragma("unroll") for (int i = 0; i < 2; ++i)                             \
      _Pragma("unroll") for (int j = 0; j < 4; ++j)                         \
          _Pragma("unroll") for (int kk = 0; kk < 2; ++kk)                  \
              acc[(mi)*2 + i][j] = __builtin_amdgcn_mfma_f32_16x16x32_bf16( \
                  AF[i][kk], Bf[j][kk], acc[(mi)*2 + i][j], 0, 0, 0);       \
  __builtin_amdgcn_s_setprio(0);

#define PHASE_SYNC_PRE                               \
  __builtin_amdgcn_s_barrier();                      \
  asm volatile("s_waitcnt lgkmcnt(0)" ::: "memory"); \
  __builtin_amdgcn_sched_barrier(0);

// proven 8-barrier body (R6-R9; frozen).
template <int PAR>
__device__ __forceinline__ void tile_body(
    int t, int NT, const __hip_bfloat16* __restrict__ Asrc,
    const __hip_bfloat16* __restrict__ Bsrc, int lda, int ldb, char* dstA,
    char* dstB, const char* ldsAr, const char* ldsBr, f32x4 (&acc)[8][4]) {
  const int tn = min(t + 1, NT - 1);
  const int tf = min(t + 2, NT - 1);
  short8 Bf[4][2], Af[2][2];

  // ph0
#pragma unroll
  for (int j = 0; j < 4; ++j)
#pragma unroll
    for (int kk = 0; kk < 2; ++kk) Bf[j][kk] = LDB_FRAG(PAR, j, kk);
#pragma unroll
  for (int i = 0; i < 2; ++i)
#pragma unroll
    for (int kk = 0; kk < 2; ++kk) Af[i][kk] = LDA_FRAG(PAR, 0, i, kk);
  STAGE_A(PAR ^ 1, 0, tn);
  PHASE_SYNC_PRE
  MFMA_ON(0, Af)
  __builtin_amdgcn_s_barrier();

  // ph1
#pragma unroll
  for (int i = 0; i < 2; ++i)
#pragma unroll
    for (int kk = 0; kk < 2; ++kk) Af[i][kk] = LDA_FRAG(PAR, 1, i, kk);
  STAGE_A(PAR ^ 1, 1, tn);
  PHASE_SYNC_PRE
  MFMA_ON(1, Af)
  __builtin_amdgcn_s_barrier();

  // ph2
#pragma unroll
  for (int i = 0; i < 2; ++i)
#pragma unroll
    for (int kk = 0; kk < 2; ++kk) Af[i][kk] = LDA_FRAG(PAR, 2, i, kk);
  STAGE_B(PAR, 0, tf);
  PHASE_SYNC_PRE
  MFMA_ON(2, Af)
  __builtin_amdgcn_s_barrier();

  // ph3
#pragma unroll
  for (int i = 0; i < 2; ++i)
#pragma unroll
    for (int kk = 0; kk < 2; ++kk) Af[i][kk] = LDA_FRAG(PAR, 3, i, kk);
  STAGE_B(PAR, 1, tf);
  PHASE_SYNC_PRE
  MFMA_ON(3, Af)
  asm volatile("s_waitcnt vmcnt(4)" ::: "memory");
  __builtin_amdgcn_s_barrier();
  __builtin_amdgcn_sched_barrier(0);
}

// C[M,N] = A[M,K] * B[N,K]^T ; 256x256 tile, BK=64, 8 waves, 16x16x32 MFMA.
// EPI 0: C bf16
// EPI 3: C bf16 = exp(acc*scale); aux = PS[NB][16][4096] row partial sums
// EPI 4: C fp32 = acc * (1/rowsum from aux=PS) + bias[col]   [rs_inv fused]
template <int EPI>
__device__ __forceinline__ void gemm8_body(
    int wgin, int nwg, const __hip_bfloat16* __restrict__ A,
    const __hip_bfloat16* __restrict__ Bm, void* __restrict__ Cv,
    const float* __restrict__ bias, float* __restrict__ aux, int N, int K,
    int lda, int ldb, int ldc, float scale, long strideA, long strideB,
    long strideC) {
  __shared__ alignas(16) char lds[131072];
  const int tid = threadIdx.x;
  const int lane = tid & 63;
  const int w = tid >> 6;
  const int wr = w >> 2, wc = w & 3;

  // XCD-contiguous transform + 4x4 supertile decode (L2 locality).
  int wg = (wgin & 7) * (nwg >> 3) + (wgin >> 3);
  const int nbn = N >> 8;
  const int nstx = nbn >> 2;
  const int st = wg >> 4;
  const int bm = (st / nstx) * 4 + ((wg >> 2) & 3);
  const int bn = (st % nstx) * 4 + (wg & 3);

  A += (long)blockIdx.y * strideA;
  Bm += (long)blockIdx.y * strideB;

  // rs_inv fused (EPI 4): load+reduce PS BEFORE staging so these vmcnt ops
  // fully retire (value consumed immediately) and never enter the counted
  // staging FIFO. One float per tid<256 covers this block's 256 rows.
  float myrsi = 0.f;
  if (EPI == 4 && tid < 256) {
    float s = 0.f;
#pragma unroll
    for (int cb = 0; cb < 16; ++cb)
      s += aux[(size_t)blockIdx.y * 65536 + cb * 4096 + bm * 256 + tid];
    myrsi = 1.0f / s;
  }

  // staging source coords (pre-swizzled column: involution of read XOR)
  const int R = ((w >> 1) << 4) + (lane >> 2);
  const int Cc = ((w & 1) << 5) + (((lane & 3) << 3) ^ ((lane & 32) >> 1));
  const __hip_bfloat16* Asrc = A + (size_t)(bm * 256 + R) * lda + Cc;
  const __hip_bfloat16* Bsrc = Bm + (size_t)(bn * 256 + R) * ldb + Cc;
  char* dstA = lds + w * 1024 + lane * 16;
  char* dstB = dstA + 65536;

  // read-side swizzled base offsets (verified conflict-free)
  const int fr = lane & 15;
  const int fk2 = (lane >> 4) << 4;
  const int rby = fr * 64 + (fk2 ^ ((fr & 8) << 2));
  const char* ldsAr = lds + wr * 16384 + rby;
  const char* ldsBr = lds + 65536 + (wc >> 1) * 16384 + (wc & 1) * 8192 + rby;

  const int NT = K >> 6;
  f32x4 acc[8][4] = {};

  // prologue: T0 all 4 halves -> par0; T1 B halves -> par1; vmcnt(4) keeps
  // T1's B (4 loads) in flight = steady state.
  STAGE_A(0, 0, 0)
  STAGE_A(0, 1, 0)
  STAGE_B(0, 0, 0)
  STAGE_B(0, 1, 0)
  STAGE_B(1, 0, 1)
  STAGE_B(1, 1, 1)
  asm volatile("s_waitcnt vmcnt(4)" ::: "memory");
  __builtin_amdgcn_s_barrier();
  __builtin_amdgcn_sched_barrier(0);

  for (int t = 0; t < NT; t += 2) {
    tile_body<0>(t, NT, Asrc, Bsrc, lda, ldb, dstA, dstB, ldsAr, ldsBr, acc);
    tile_body<1>(t + 1, NT, Asrc, Bsrc, lda, ldb, dstA, dstB, ldsAr, ldsBr,
                 acc);
  }
  asm volatile("s_waitcnt vmcnt(0)" ::: "memory");

  // epilogue: C/D layout col=lane&15, row=(lane>>4)*4+reg  [verified m89/m91]
  float* Cf = (float*)Cv;
  __hip_bfloat16* Cb = (__hip_bfloat16*)Cv;
  const size_t cbase = (size_t)blockIdx.y * (size_t)strideC;
  const int r0 = bm * 256 + wr * 128 + ((lane >> 4) << 2);
  const int c0 = bn * 256 + wc * 64 + fr;

  if (EPI == 3) {
    __syncthreads();
    float* rpart = (float*)lds;  // [4 wc][256 blockrow]
#pragma unroll
    for (int mi = 0; mi < 4; ++mi) {
      float pr[8] = {};
#pragma unroll
      for (int i = 0; i < 2; ++i)
#pragma unroll
        for (int j = 0; j < 4; ++j) {
          const int row = r0 + mi * 32 + i * 16;
          const int col = c0 + j * 16;
#pragma unroll
          for (int r = 0; r < 4; ++r) {
            const float p = __expf(acc[mi * 2 + i][j][r] * scale);
            Cb[cbase + (size_t)(row + r) * ldc + col] = __float2bfloat16(p);
            pr[i * 4 + r] += p;
          }
        }
#pragma unroll
      for (int k = 0; k < 8; ++k) {
#pragma unroll
        for (int m = 1; m <= 8; m <<= 1) pr[k] += __shfl_xor(pr[k], m);
      }
      if (fr == 0) {
#pragma unroll
        for (int i = 0; i < 2; ++i)
#pragma unroll
          for (int r = 0; r < 4; ++r)
            rpart[wc * 256 + wr * 128 + mi * 32 + i * 16 +
                  ((lane >> 4) << 2) + r] = pr[i * 4 + r];
      }
    }
    __syncthreads();
    if (tid < 256) {
      const float s = rpart[tid] + rpart[256 + tid] + rpart[512 + tid] +
                      rpart[768 + tid];
      aux[(size_t)blockIdx.y * 65536 + (size_t)bn * 4096 + bm * 256 + tid] = s;
    }
    return;
  }

  if (EPI == 4) {
    // distribute myrsi (tid<256 holds row bm*256+tid) to all waves via LDS
    __syncthreads();
    float* ldsf = (float*)lds;
    if (tid < 256) ldsf[tid] = myrsi;
    __syncthreads();
#pragma unroll
    for (int mi = 0; mi < 4; ++mi)
#pragma unroll
      for (int i = 0; i < 2; ++i) {
        float rsv[4];
#pragma unroll
        for (int r = 0; r < 4; ++r)
          rsv[r] =
              ldsf[wr * 128 + mi * 32 + i * 16 + ((lane >> 4) << 2) + r];
#pragma unroll
        for (int j = 0; j < 4; ++j) {
          const int row = r0 + mi * 32 + i * 16;
          const int col = c0 + j * 16;
#pragma unroll
          for (int r = 0; r < 4; ++r)
            Cf[cbase + (size_t)(row + r) * ldc + col] =
                acc[mi * 2 + i][j][r] * rsv[r] + bias[col];
        }
      }
    return;
  }

#pragma unroll
  for (int mi = 0; mi < 4; ++mi)
#pragma unroll
    for (int i = 0; i < 2; ++i)
#pragma unroll
      for (int j = 0; j < 4; ++j) {
        const int row = r0 + mi * 32 + i * 16;
        const int col = c0 + j * 16;
#pragma unroll
        for (int r = 0; r < 4; ++r)
          Cb[cbase + (size_t)(row + r) * ldc + col] =
              __float2bfloat16(acc[mi * 2 + i][j][r]);
      }
}

#define GEMM_WRAP(NAME, EPI)                                                   \
  __global__ __launch_bounds__(512, 1) void NAME(                              \
      const __hip_bfloat16* __restrict__ A,                                    \
      const __hip_bfloat16* __restrict__ Bm, void* __restrict__ Cv,            \
      const float* __restrict__ bias, float* __restrict__ aux, int N, int K,   \
      int lda, int ldb, int ldc, float scale, long strideA, long strideB,      \
      long strideC) {                                                          \
    gemm8_body<EPI>(blockIdx.x, gridDim.x, A, Bm, Cv, bias, aux, N, K, lda,    \
                    ldb, ldc, scale, strideA, strideB, strideC);               \
  }
GEMM_WRAP(g_qkt, 3)  // P_b = exp(...), + PS row sums
GEMM_WRAP(g_pv, 4)   // out_b = acc * (1/rowsum(PS)) + bo   [rs_inv fused]

// g_small + x-cast mixed dispatch. Grid (64 + 2048, 2), 512 threads.
//   b < 64 : y=0 -> Gt = bt(WkT, WqT); y=1 -> Wvo = bt(Wob, WvT)  (2048^3)
//   b >= 64: x-cast, 8192 f32 -> bf16 per block (512 thr x 16 elems)
__global__ __launch_bounds__(512, 1) void g_small_x(
    const __hip_bfloat16* __restrict__ WA, const __hip_bfloat16* __restrict__ WB,
    __hip_bfloat16* __restrict__ WC, long wstride,
    const float* __restrict__ x, __hip_bfloat16* __restrict__ xb) {
  const int b = blockIdx.x;
  if (b < 64) {
    gemm8_body<0>(b, 64, WA, WB, WC, nullptr, nullptr, 2048, 2048, 2048, 2048,
                  2048, 1.f, wstride, wstride, wstride);
    return;
  }
  const long ci = (long)blockIdx.y * 2048 + (b - 64);
  const long base = ci * 8192 + (long)threadIdx.x * 16;
#pragma unroll
  for (int h = 0; h < 2; ++h) {
    const f32x4 a = *(const f32x4*)(x + base + h * 8);
    const f32x4 c = *(const f32x4*)(x + base + h * 8 + 4);
    ushort8 o;
#pragma unroll
    for (int j = 0; j < 4; ++j) o[j] = f2bf(a[j]);
#pragma unroll
    for (int j = 0; j < 4; ++j) o[4 + j] = f2bf(c[j]);
    *(ushort8*)(xb + base + h * 8) = o;
  }
}

// merged xG + VOt dispatch (independent GEMMs, one launch)
__global__ __launch_bounds__(512, 1) void g_xgvot(
    const __hip_bfloat16* __restrict__ Xb, const __hip_bfloat16* __restrict__ Gt,
    __hip_bfloat16* __restrict__ xG, const __hip_bfloat16* __restrict__ Wvo,
    __hip_bfloat16* __restrict__ VOt) {
  const int b = blockIdx.x;
  const __hip_bfloat16 *Ap, *Bp;
  __hip_bfloat16* Cp;
  int wg, nwg, N, ldc;
  if (b < 512) {  // xG = bt(Xb, Gt): [16384, 2048], K=2048
    Ap = Xb; Bp = Gt; Cp = xG;
    wg = b; nwg = 512; N = 2048; ldc = 2048;
  } else {        // VOt_y = bt(Wvo, Xb_y): [2048, 4096] x4, K=2048
    const int vb = b - 512;
    const int y = vb >> 7;
    Ap = Wvo; Bp = Xb + (size_t)y * S_ * DM_; Cp = VOt + (size_t)y * DA_ * S_;
    wg = vb & 127; nwg = 128; N = 4096; ldc = 4096;
  }
  gemm8_body<0>(wg, nwg, Ap, Bp, Cp, nullptr, nullptr, N, 2048, 2048, 2048,
                ldc, 1.f, 0, 0, 0);
}

// transpose-cast one 64x64 tile of a 2048x2048 f32 matrix -> bf16 transposed
__device__ __forceinline__ void tcast64(const float* __restrict__ src,
                                        __hip_bfloat16* __restrict__ dst,
                                        int tile) {
  __shared__ __hip_bfloat16 lt[64][65];
  const int ti = tile >> 5;
  const int tj = tile & 31;
  const int t = threadIdx.x;
  const int r = t >> 4;
  const int c4 = (t & 15) * 4;
#pragma unroll
  for (int rr = 0; rr < 4; ++rr) {
    const int row = ti * 64 + rr * 16 + r;
    const f32x4 v = *(const f32x4*)(src + (size_t)row * 2048 + tj * 64 + c4);
#pragma unroll
    for (int k = 0; k < 4; ++k)
      lt[c4 + k][rr * 16 + r] = __float2bfloat16(v[k]);
  }
  __syncthreads();
  const int a = t >> 2;
  const int b16 = (t & 3) * 16;
  ushort8* dp = (ushort8*)(dst + (size_t)(tj * 64 + a) * 2048 + ti * 64 + b16);
  const unsigned short* lp = (const unsigned short*)&lt[a][b16];
  ushort8 o0, o1;
#pragma unroll
  for (int k = 0; k < 8; ++k) {
    o0[k] = lp[k];
    o1[k] = lp[8 + k];
  }
  dp[0] = o0;
  dp[1] = o1;
}

// weights only: Wq/Wk/Wv transpose-cast (1024 blocks each) + Wo plain (2048)
__global__ __launch_bounds__(256) void cast_w(
    const float* __restrict__ wq, const float* __restrict__ wk,
    const float* __restrict__ wv, const float* __restrict__ wo,
    __hip_bfloat16* __restrict__ wqt, __hip_bfloat16* __restrict__ wkt,
    __hip_bfloat16* __restrict__ wvt, __hip_bfloat16* __restrict__ wob) {
  const int b = blockIdx.x;
  if (b < 1024) { tcast64(wq, wqt, b); return; }
  if (b < 2048) { tcast64(wk, wkt, b - 1024); return; }
  if (b < 3072) { tcast64(wv, wvt, b - 2048); return; }
  const long i = ((long)(b - 3072) * 256 + threadIdx.x) * 8;
  const f32x4 a = *(const f32x4*)(wo + i);
  const f32x4 c = *(const f32x4*)(wo + i + 4);
  ushort8 o;
#pragma unroll
  for (int j = 0; j < 4; ++j) o[j] = f2bf(a[j]);
#pragma unroll
  for (int j = 0; j < 4; ++j) o[4 + j] = f2bf(c[j]);
  *(ushort8*)(wob + i) = o;
}

extern "C" void kernel_launch(void* const* d_in, const int* in_sizes, int n_in,
                              void* d_out, int out_size, void* d_ws,
                              size_t ws_size, hipStream_t stream) {
  (void)in_sizes; (void)n_in; (void)out_size; (void)ws_size;
  const float* x = (const float*)d_in[0];
  const float* Wq = (const float*)d_in[1];
  const float* Wk = (const float*)d_in[2];
  const float* Wv = (const float*)d_in[3];
  const float* Wo = (const float*)d_in[4];
  const float* bo = (const float*)d_in[5];
  float* out = (float*)d_out;

  const long MB = 1ll << 20;
  char* ws = (char*)d_ws;  // 370 MiB
  __hip_bfloat16* Xb  = (__hip_bfloat16*)(ws);             // 64 MiB
  __hip_bfloat16* xG  = (__hip_bfloat16*)(ws + 64 * MB);   // 64 MiB
  __hip_bfloat16* VOt = (__hip_bfloat16*)(ws + 128 * MB);  // 64 MiB
  __hip_bfloat16* WkT = (__hip_bfloat16*)(ws + 192 * MB);  // 8 MiB  [smallA y0]
  __hip_bfloat16* Wob = (__hip_bfloat16*)(ws + 200 * MB);  // 8 MiB  [smallA y1]
  __hip_bfloat16* WqT = (__hip_bfloat16*)(ws + 208 * MB);  // 8 MiB  [smallB y0]
  __hip_bfloat16* WvT = (__hip_bfloat16*)(ws + 216 * MB);  // 8 MiB  [smallB y1]
  __hip_bfloat16* Gt  = (__hip_bfloat16*)(ws + 224 * MB);  // 8 MiB  [smallC y0]
  __hip_bfloat16* Wvo = (__hip_bfloat16*)(ws + 232 * MB);  // 8 MiB  [smallC y1]
  char* LgP           = ws + 240 * MB;                     // 128 MiB (P bf16)
  float* PS           = (float*)(ws + 368 * MB);           // 1 MiB

  const long WSTRIDE = 8 * MB / 2;  // elements between y=0 / y=1 operands

  // weights: transpose-cast Wq/Wk/Wv, plain-cast Wo
  cast_w<<<dim3(5120), dim3(256), 0, stream>>>(Wq, Wk, Wv, Wo, WqT, WkT, WvT,
                                               Wob);
  // {Gt, Wvo} GEMMs + x-cast in one dispatch (fills all 256 CUs)
  g_small_x<<<dim3(2112, 2), dim3(512), 0, stream>>>(WkT, WqT, Gt, WSTRIDE, x,
                                                     Xb);
  // xG = bt(Xb, Gt) and VOt_b = bt(Wvo, Xb_b) merged (independent)
  g_xgvot<<<dim3(1024, 1), dim3(512), 0, stream>>>(Xb, Gt, xG, Wvo, VOt);

  const float scale = 0.022097086912079608f;  // 1/sqrt(d_model=2048)
  // P_b = exp(bt(xG_b, Xb_b)*scale) -> bf16 [4096,4096] x4 ; PS row sums
  g_qkt<<<dim3(256, NB_), dim3(512), 0, stream>>>(
      xG, Xb, LgP, nullptr, PS, 4096, 2048, 2048, 2048, 4096, scale,
      (long)S_ * DA_, (long)S_ * DM_, (long)S_ * S_);
  // out_b = bt(P_b, VOt_b) * (1/rowsum(PS)) + bo -> fp32 [4096,2048] x4
  g_pv<<<dim3(128, NB_), dim3(512), 0, stream>>>(
      (const __hip_bfloat16*)LgP, VOt, out, bo, PS, 2048, 4096, 4096, 4096,
      2048, 1.f, (long)S_ * S_, (long)DA_ * S_, (long)S_ * DM_);
}

// Round 12
// 778.307 us; speedup vs baseline: 1.0162x; 1.0033x over previous
//
#include <hip/hip_runtime.h>
#include <hip/hip_bf16.h>

// ---------------------------------------------------------------------------
// Attention (B=4, S=4096, d_model=d_attn=2048), fp32 in/out, bf16 MFMA.
// R11: persistent multi-tile GEMM blocks. Grid = 256 blocks (1 full round);
//      each block runs T tiles; tile r+1's prologue (12 global_load_lds) is
//      issued BEFORE tile r's epilogue, hiding prologue latency under the
//      epilogue. Epilogue LDS scratch moved to the A-par1 hole [32K,64K)
//      (prologue writes [0,32K) + [64K,128K) only). K-loop core frozen
//      (6 nulls). Algebra as R6-R10: Gt=bt(WkT,WqT), Wvo=bt(Wob,WvT),
//      xG=bt(Xb,Gt), VOt=bt(Wvo,Xb_b), P=exp(bt(xG_b,Xb_b)*scale)+PS,
//      out=bt(P_b,VOt_b)*(1/rowsum PS)+bo. x-cast fused into g_small_x.
// Workspace: 370 MiB.
// ---------------------------------------------------------------------------

#define S_ 4096
#define DM_ 2048
#define DA_ 2048
#define NB_ 4

typedef __attribute__((ext_vector_type(8))) short short8;
typedef __attribute__((ext_vector_type(4))) float f32x4;
typedef __attribute__((ext_vector_type(8))) unsigned short ushort8;

__device__ __forceinline__ void gload_lds16(const void* g, void* l) {
  __builtin_amdgcn_global_load_lds(
      (const __attribute__((address_space(1))) void*)g,
      (__attribute__((address_space(3))) void*)l, 16, 0, 0);
}

__device__ __forceinline__ unsigned short f2bf(float f) {
  __hip_bfloat16 h = __float2bfloat16(f);
  return __builtin_bit_cast(unsigned short, h);
}

#define STAGE_A(par, h, kt)                                                    \
  {                                                                            \
    const __hip_bfloat16* s0 = Asrc + (size_t)((h)*128) * lda + (kt)*64;       \
    gload_lds16(s0, dstA + (par)*32768 + (h)*16384);                           \
    gload_lds16(s0 + (size_t)64 * lda, dstA + (par)*32768 + (h)*16384 + 8192); \
  }
#define STAGE_B(par, h, kt)                                                    \
  {                                                                            \
    const __hip_bfloat16* s0 = Bsrc + (size_t)((h)*128) * ldb + (kt)*64;       \
    gload_lds16(s0, dstB + (par)*32768 + (h)*16384);                           \
    gload_lds16(s0 + (size_t)64 * ldb, dstB + (par)*32768 + (h)*16384 + 8192); \
  }
#define LDA_FRAG(par, mi, i, kk) \
  (*(const short8*)(ldsAr + (par)*32768 + ((mi)*2 + (i)) * 2048 + (kk)*1024))
#define LDB_FRAG(par, j, kk) \
  (*(const short8*)(ldsBr + (par)*32768 + (j)*2048 + (kk)*1024))

#define MFMA_ON(mi, AF)                                                     \
  __builtin_amdgcn_s_setprio(1);                                            \
  _Pragma("unroll") for (int i = 0; i < 2; ++i)                             \
      _Pragma("unroll") for (int j = 0; j < 4; ++j)                         \
          _Pragma("unroll") for (int kk = 0; kk < 2; ++kk)                  \
              acc[(mi)*2 + i][j] = __builtin_amdgcn_mfma_f32_16x16x32_bf16( \
                  AF[i][kk], Bf[j][kk], acc[(mi)*2 + i][j], 0, 0, 0);       \
  __builtin_amdgcn_s_setprio(0);

#define PHASE_SYNC_PRE                               \
  __builtin_amdgcn_s_barrier();                      \
  asm volatile("s_waitcnt lgkmcnt(0)" ::: "memory"); \
  __builtin_amdgcn_sched_barrier(0);

#define VM4_BARRIER                                   \
  asm volatile("s_waitcnt vmcnt(4)" ::: "memory");    \
  __builtin_amdgcn_s_barrier();                       \
  __builtin_amdgcn_sched_barrier(0);

// proven 8-barrier body (frozen since R6).
template <int PAR>
__device__ __forceinline__ void tile_body(
    int t, int NT, const __hip_bfloat16* __restrict__ Asrc,
    const __hip_bfloat16* __restrict__ Bsrc, int lda, int ldb, char* dstA,
    char* dstB, const char* ldsAr, const char* ldsBr, f32x4 (&acc)[8][4]) {
  const int tn = min(t + 1, NT - 1);
  const int tf = min(t + 2, NT - 1);
  short8 Bf[4][2], Af[2][2];

  // ph0
#pragma unroll
  for (int j = 0; j < 4; ++j)
#pragma unroll
    for (int kk = 0; kk < 2; ++kk) Bf[j][kk] = LDB_FRAG(PAR, j, kk);
#pragma unroll
  for (int i = 0; i < 2; ++i)
#pragma unroll
    for (int kk = 0; kk < 2; ++kk) Af[i][kk] = LDA_FRAG(PAR, 0, i, kk);
  STAGE_A(PAR ^ 1, 0, tn);
  PHASE_SYNC_PRE
  MFMA_ON(0, Af)
  __builtin_amdgcn_s_barrier();

  // ph1
#pragma unroll
  for (int i = 0; i < 2; ++i)
#pragma unroll
    for (int kk = 0; kk < 2; ++kk) Af[i][kk] = LDA_FRAG(PAR, 1, i, kk);
  STAGE_A(PAR ^ 1, 1, tn);
  PHASE_SYNC_PRE
  MFMA_ON(1, Af)
  __builtin_amdgcn_s_barrier();

  // ph2
#pragma unroll
  for (int i = 0; i < 2; ++i)
#pragma unroll
    for (int kk = 0; kk < 2; ++kk) Af[i][kk] = LDA_FRAG(PAR, 2, i, kk);
  STAGE_B(PAR, 0, tf);
  PHASE_SYNC_PRE
  MFMA_ON(2, Af)
  __builtin_amdgcn_s_barrier();

  // ph3
#pragma unroll
  for (int i = 0; i < 2; ++i)
#pragma unroll
    for (int kk = 0; kk < 2; ++kk) Af[i][kk] = LDA_FRAG(PAR, 3, i, kk);
  STAGE_B(PAR, 1, tf);
  PHASE_SYNC_PRE
  MFMA_ON(3, Af)
  VM4_BARRIER
}

struct Lane {
  int tid, lane, w, wr, wc, fr;
  int R, Cc;
  char *lds, *dstA, *dstB;
  const char *ldsAr, *ldsBr;
};

__device__ __forceinline__ void lane_setup(char* lds, Lane& L) {
  L.lds = lds;
  L.tid = threadIdx.x;
  L.lane = L.tid & 63;
  L.w = L.tid >> 6;
  L.wr = L.w >> 2;
  L.wc = L.w & 3;
  L.fr = L.lane & 15;
  L.R = ((L.w >> 1) << 4) + (L.lane >> 2);
  L.Cc = ((L.w & 1) << 5) + (((L.lane & 3) << 3) ^ ((L.lane & 32) >> 1));
  L.dstA = lds + L.w * 1024 + L.lane * 16;
  L.dstB = L.dstA + 65536;
  const int fk2 = (L.lane >> 4) << 4;
  const int rby = L.fr * 64 + (fk2 ^ ((L.fr & 8) << 2));
  L.ldsAr = lds + L.wr * 16384 + rby;
  L.ldsBr = lds + 65536 + (L.wc >> 1) * 16384 + (L.wc & 1) * 8192 + rby;
}

// XCD-contiguous transform + 4x4 supertile (requires nwg%8==0, nbm%4, nbn%4)
__device__ __forceinline__ void decode_tile(int v, int nwg, int N, int& bm,
                                            int& bn) {
  const int wg = (v & 7) * (nwg >> 3) + (v >> 3);
  const int nbn = N >> 8, nstx = nbn >> 2, st = wg >> 4;
  bm = (st / nstx) * 4 + ((wg >> 2) & 3);
  bn = (st % nstx) * 4 + (wg & 3);
}

__device__ __forceinline__ void prologue_issue(
    const __hip_bfloat16* __restrict__ Asrc,
    const __hip_bfloat16* __restrict__ Bsrc, int lda, int ldb, char* dstA,
    char* dstB) {
  STAGE_A(0, 0, 0)
  STAGE_A(0, 1, 0)
  STAGE_B(0, 0, 0)
  STAGE_B(0, 1, 0)
  STAGE_B(1, 0, 1)
  STAGE_B(1, 1, 1)
}

__device__ __forceinline__ void kloop(int NT,
                                      const __hip_bfloat16* __restrict__ Asrc,
                                      const __hip_bfloat16* __restrict__ Bsrc,
                                      int lda, int ldb, const Lane& L,
                                      f32x4 (&acc)[8][4]) {
  char* dstA = L.dstA;
  char* dstB = L.dstB;
  const char* ldsAr = L.ldsAr;
  const char* ldsBr = L.ldsBr;
  for (int t = 0; t < NT; t += 2) {
    tile_body<0>(t, NT, Asrc, Bsrc, lda, ldb, dstA, dstB, ldsAr, ldsBr, acc);
    tile_body<1>(t + 1, NT, Asrc, Bsrc, lda, ldb, dstA, dstB, ldsAr, ldsBr,
                 acc);
  }
}

__device__ __forceinline__ void acc_zero(f32x4 (&acc)[8][4]) {
  const f32x4 z = {0.f, 0.f, 0.f, 0.f};
#pragma unroll
  for (int a = 0; a < 8; ++a)
#pragma unroll
    for (int j = 0; j < 4; ++j) acc[a][j] = z;
}

// EPI0: plain bf16 store. C/D layout col=lane&15, row=(lane>>4)*4+reg.
__device__ __forceinline__ void epi_bf16(f32x4 (&acc)[8][4],
                                         __hip_bfloat16* __restrict__ Cb,
                                         int ldc, const Lane& L, int bm,
                                         int bn) {
  const int r0 = bm * 256 + L.wr * 128 + ((L.lane >> 4) << 2);
  const int c0 = bn * 256 + L.wc * 64 + L.fr;
#pragma unroll
  for (int mi = 0; mi < 4; ++mi)
#pragma unroll
    for (int i = 0; i < 2; ++i)
#pragma unroll
      for (int j = 0; j < 4; ++j) {
        const int row = r0 + mi * 32 + i * 16;
        const int col = c0 + j * 16;
#pragma unroll
        for (int r = 0; r < 4; ++r)
          Cb[(size_t)(row + r) * ldc + col] =
              __float2bfloat16(acc[mi * 2 + i][j][r]);
      }
}

// EPI3: P = bf16(exp(acc*scale)); auxw[tid] (tid<256) = row partial sums.
// LDS scratch at +32768 (A-par1 hole; disjoint from in-flight prologue DMA).
__device__ __forceinline__ void epi_exp(f32x4 (&acc)[8][4],
                                        __hip_bfloat16* __restrict__ Cb,
                                        int ldc, float scale,
                                        float* __restrict__ auxw,
                                        const Lane& L, int bm, int bn) {
  const int r0 = bm * 256 + L.wr * 128 + ((L.lane >> 4) << 2);
  const int c0 = bn * 256 + L.wc * 64 + L.fr;
  float* rpart = (float*)(L.lds + 32768);  // [4 wc][256 localrow]
  __syncthreads();
#pragma unroll
  for (int mi = 0; mi < 4; ++mi) {
    float pr[8] = {};
#pragma unroll
    for (int i = 0; i < 2; ++i)
#pragma unroll
      for (int j = 0; j < 4; ++j) {
        const int row = r0 + mi * 32 + i * 16;
        const int col = c0 + j * 16;
#pragma unroll
        for (int r = 0; r < 4; ++r) {
          const float p = __expf(acc[mi * 2 + i][j][r] * scale);
          Cb[(size_t)(row + r) * ldc + col] = __float2bfloat16(p);
          pr[i * 4 + r] += p;
        }
      }
#pragma unroll
    for (int k = 0; k < 8; ++k) {
#pragma unroll
      for (int m = 1; m <= 8; m <<= 1) pr[k] += __shfl_xor(pr[k], m);
    }
    if (L.fr == 0) {
#pragma unroll
      for (int i = 0; i < 2; ++i)
#pragma unroll
        for (int r = 0; r < 4; ++r)
          rpart[L.wc * 256 + L.wr * 128 + mi * 32 + i * 16 +
                ((L.lane >> 4) << 2) + r] = pr[i * 4 + r];
    }
  }
  __syncthreads();
  if (L.tid < 256) {
    const float s = rpart[L.tid] + rpart[256 + L.tid] + rpart[512 + L.tid] +
                    rpart[768 + L.tid];
    auxw[L.tid] = s;
  }
}

// EPI4: out = acc * myrsi(row) + bias[col]; myrsi distributed via LDS +32768.
__device__ __forceinline__ void epi_norm(f32x4 (&acc)[8][4],
                                         float* __restrict__ Cf, int ldc,
                                         const float* __restrict__ bias,
                                         float myrsi, const Lane& L, int bm,
                                         int bn) {
  const int r0 = bm * 256 + L.wr * 128 + ((L.lane >> 4) << 2);
  const int c0 = bn * 256 + L.wc * 64 + L.fr;
  float* ldsf = (float*)(L.lds + 32768);
  __syncthreads();
  if (L.tid < 256) ldsf[L.tid] = myrsi;
  __syncthreads();
#pragma unroll
  for (int mi = 0; mi < 4; ++mi)
#pragma unroll
    for (int i = 0; i < 2; ++i) {
      float rsv[4];
#pragma unroll
      for (int r = 0; r < 4; ++r)
        rsv[r] =
            ldsf[L.wr * 128 + mi * 32 + i * 16 + ((L.lane >> 4) << 2) + r];
#pragma unroll
      for (int j = 0; j < 4; ++j) {
        const int row = r0 + mi * 32 + i * 16;
        const int col = c0 + j * 16;
#pragma unroll
        for (int r = 0; r < 4; ++r)
          Cf[(size_t)(row + r) * ldc + col] =
              acc[mi * 2 + i][j][r] * rsv[r] + bias[col];
      }
    }
}

// ---- persistent kernels ---------------------------------------------------

// P_b = exp(bt(xG_b, Xb_b)*scale), + PS row sums. grid (64, NB), T=4.
__global__ __launch_bounds__(512, 1) void g_qkt(
    const __hip_bfloat16* __restrict__ xG, const __hip_bfloat16* __restrict__ Xb,
    __hip_bfloat16* __restrict__ P, float* __restrict__ PS) {
  __shared__ alignas(16) char lds[131072];
  Lane L;
  lane_setup(lds, L);
  const __hip_bfloat16* Ab = xG + (size_t)blockIdx.y * S_ * DA_;
  const __hip_bfloat16* Bb = Xb + (size_t)blockIdx.y * S_ * DM_;
  __hip_bfloat16* Cb = P + (size_t)blockIdx.y * S_ * S_;
  float* PSb = PS + (size_t)blockIdx.y * 65536;
  const float scale = 0.022097086912079608f;  // 1/sqrt(2048)

  int bm, bn;
  decode_tile((int)blockIdx.x, 256, 4096, bm, bn);
  const __hip_bfloat16* Asrc = Ab + (size_t)(bm * 256 + L.R) * 2048 + L.Cc;
  const __hip_bfloat16* Bsrc = Bb + (size_t)(bn * 256 + L.R) * 2048 + L.Cc;
  prologue_issue(Asrc, Bsrc, 2048, 2048, L.dstA, L.dstB);
  VM4_BARRIER

  f32x4 acc[8][4];
  for (int r = 0;; ++r) {
    acc_zero(acc);
    kloop(32, Asrc, Bsrc, 2048, 2048, L, acc);
    const bool more = (r + 1 < 4);
    int nbm = 0, nbn = 0;
    const __hip_bfloat16 *nA = nullptr, *nB = nullptr;
    if (more) {
      decode_tile((int)blockIdx.x + (r + 1) * 64, 256, 4096, nbm, nbn);
      nA = Ab + (size_t)(nbm * 256 + L.R) * 2048 + L.Cc;
      nB = Bb + (size_t)(nbn * 256 + L.R) * 2048 + L.Cc;
      prologue_issue(nA, nB, 2048, 2048, L.dstA, L.dstB);
    }
    epi_exp(acc, Cb, 4096, scale, PSb + bn * 4096 + bm * 256, L, bm, bn);
    if (!more) break;
    VM4_BARRIER
    bm = nbm; bn = nbn; Asrc = nA; Bsrc = nB;
  }
}

// out_b = bt(P_b, VOt_b) * (1/rowsum(PS)) + bo. grid (64, NB), T=2, K=4096.
__global__ __launch_bounds__(512, 1) void g_pv(
    const __hip_bfloat16* __restrict__ P, const __hip_bfloat16* __restrict__ VOt,
    float* __restrict__ out, const float* __restrict__ bo,
    const float* __restrict__ PS) {
  __shared__ alignas(16) char lds[131072];
  Lane L;
  lane_setup(lds, L);
  const __hip_bfloat16* Ab = P + (size_t)blockIdx.y * S_ * S_;
  const __hip_bfloat16* Bb = VOt + (size_t)blockIdx.y * DA_ * S_;
  float* Cf = out + (size_t)blockIdx.y * S_ * DM_;
  const float* PSb = PS + (size_t)blockIdx.y * 65536;

  int bm, bn;
  decode_tile((int)blockIdx.x, 128, 2048, bm, bn);
  const __hip_bfloat16* Asrc = Ab + (size_t)(bm * 256 + L.R) * 4096 + L.Cc;
  const __hip_bfloat16* Bsrc = Bb + (size_t)(bn * 256 + L.R) * 4096 + L.Cc;
  prologue_issue(Asrc, Bsrc, 4096, 4096, L.dstA, L.dstB);
  VM4_BARRIER

  f32x4 acc[8][4];
  for (int r = 0;; ++r) {
    acc_zero(acc);
    kloop(64, Asrc, Bsrc, 4096, 4096, L, acc);
    float myrsi = 0.f;
    if (L.tid < 256) {
      float s = 0.f;
#pragma unroll
      for (int cb = 0; cb < 16; ++cb)
        s += PSb[cb * 4096 + bm * 256 + L.tid];
      myrsi = 1.0f / s;
    }
    const bool more = (r + 1 < 2);
    int nbm = 0, nbn = 0;
    const __hip_bfloat16 *nA = nullptr, *nB = nullptr;
    if (more) {
      decode_tile((int)blockIdx.x + (r + 1) * 64, 128, 2048, nbm, nbn);
      nA = Ab + (size_t)(nbm * 256 + L.R) * 4096 + L.Cc;
      nB = Bb + (size_t)(nbn * 256 + L.R) * 4096 + L.Cc;
      prologue_issue(nA, nB, 4096, 4096, L.dstA, L.dstB);
    }
    epi_norm(acc, Cf, 2048, bo, myrsi, L, bm, bn);
    if (!more) break;
    VM4_BARRIER
    bm = nbm; bn = nbn; Asrc = nA; Bsrc = nB;
  }
}

// xG = bt(Xb, Gt) [512 tiles] + VOt_y = bt(Wvo, Xb_y) [512 tiles].
// grid (256), T=4, virtual id v = b + r*256.
__global__ __launch_bounds__(512, 1) void g_xgvot(
    const __hip_bfloat16* __restrict__ Xb, const __hip_bfloat16* __restrict__ Gt,
    __hip_bfloat16* __restrict__ xG, const __hip_bfloat16* __restrict__ Wvo,
    __hip_bfloat16* __restrict__ VOt) {
  __shared__ alignas(16) char lds[131072];
  Lane L;
  lane_setup(lds, L);

  auto dec = [&](int v, const __hip_bfloat16*& As, const __hip_bfloat16*& Bs,
                 __hip_bfloat16*& Cp, int& ldc_, int& bm_, int& bn_) {
    if (v < 512) {
      decode_tile(v, 512, 2048, bm_, bn_);
      As = Xb + (size_t)(bm_ * 256 + L.R) * 2048 + L.Cc;
      Bs = Gt + (size_t)(bn_ * 256 + L.R) * 2048 + L.Cc;
      Cp = xG;
      ldc_ = 2048;
    } else {
      const int y = (v - 512) >> 7;
      decode_tile((v - 512) & 127, 128, 4096, bm_, bn_);
      As = Wvo + (size_t)(bm_ * 256 + L.R) * 2048 + L.Cc;
      Bs = Xb + (size_t)y * S_ * DM_ + (size_t)(bn_ * 256 + L.R) * 2048 + L.Cc;
      Cp = VOt + (size_t)y * DA_ * S_;
      ldc_ = 4096;
    }
  };

  int bm, bn, ldc;
  const __hip_bfloat16 *Asrc, *Bsrc;
  __hip_bfloat16* Cp;
  dec((int)blockIdx.x, Asrc, Bsrc, Cp, ldc, bm, bn);
  prologue_issue(Asrc, Bsrc, 2048, 2048, L.dstA, L.dstB);
  VM4_BARRIER

  f32x4 acc[8][4];
  for (int r = 0;; ++r) {
    acc_zero(acc);
    kloop(32, Asrc, Bsrc, 2048, 2048, L, acc);
    const bool more = (r + 1 < 4);
    int nbm = 0, nbn = 0, nldc = 0;
    const __hip_bfloat16 *nA = nullptr, *nB = nullptr;
    __hip_bfloat16* nC = nullptr;
    if (more) {
      dec((int)blockIdx.x + (r + 1) * 256, nA, nB, nC, nldc, nbm, nbn);
      prologue_issue(nA, nB, 2048, 2048, L.dstA, L.dstB);
    }
    epi_bf16(acc, Cp, ldc, L, bm, bn);
    if (!more) break;
    VM4_BARRIER
    bm = nbm; bn = nbn; ldc = nldc; Asrc = nA; Bsrc = nB; Cp = nC;
  }
}

// {Gt, Wvo} GEMMs (blocks 0-63, y in {0,1}) + x-cast (blocks 64+).
__global__ __launch_bounds__(512, 1) void g_small_x(
    const __hip_bfloat16* __restrict__ WA, const __hip_bfloat16* __restrict__ WB,
    __hip_bfloat16* __restrict__ WC, long wstride,
    const float* __restrict__ x, __hip_bfloat16* __restrict__ xb) {
  const int b = blockIdx.x;
  if (b < 64) {
    __shared__ alignas(16) char lds[131072];
    Lane L;
    lane_setup(lds, L);
    const __hip_bfloat16* Ab = WA + (size_t)blockIdx.y * wstride;
    const __hip_bfloat16* Bb = WB + (size_t)blockIdx.y * wstride;
    __hip_bfloat16* Cb = WC + (size_t)blockIdx.y * wstride;
    int bm, bn;
    decode_tile(b, 64, 2048, bm, bn);
    const __hip_bfloat16* Asrc = Ab + (size_t)(bm * 256 + L.R) * 2048 + L.Cc;
    const __hip_bfloat16* Bsrc = Bb + (size_t)(bn * 256 + L.R) * 2048 + L.Cc;
    prologue_issue(Asrc, Bsrc, 2048, 2048, L.dstA, L.dstB);
    VM4_BARRIER
    f32x4 acc[8][4];
    acc_zero(acc);
    kloop(32, Asrc, Bsrc, 2048, 2048, L, acc);
    epi_bf16(acc, Cb, 2048, L, bm, bn);
    return;
  }
  const long ci = (long)blockIdx.y * 2048 + (b - 64);
  const long base = ci * 8192 + (long)threadIdx.x * 16;
#pragma unroll
  for (int h = 0; h < 2; ++h) {
    const f32x4 a = *(const f32x4*)(x + base + h * 8);
    const f32x4 c = *(const f32x4*)(x + base + h * 8 + 4);
    ushort8 o;
#pragma unroll
    for (int j = 0; j < 4; ++j) o[j] = f2bf(a[j]);
#pragma unroll
    for (int j = 0; j < 4; ++j) o[4 + j] = f2bf(c[j]);
    *(ushort8*)(xb + base + h * 8) = o;
  }
}

// transpose-cast one 64x64 tile of a 2048x2048 f32 matrix -> bf16 transposed
__device__ __forceinline__ void tcast64(const float* __restrict__ src,
                                        __hip_bfloat16* __restrict__ dst,
                                        int tile) {
  __shared__ __hip_bfloat16 lt[64][65];
  const int ti = tile >> 5;
  const int tj = tile & 31;
  const int t = threadIdx.x;
  const int r = t >> 4;
  const int c4 = (t & 15) * 4;
#pragma unroll
  for (int rr = 0; rr < 4; ++rr) {
    const int row = ti * 64 + rr * 16 + r;
    const f32x4 v = *(const f32x4*)(src + (size_t)row * 2048 + tj * 64 + c4);
#pragma unroll
    for (int k = 0; k < 4; ++k)
      lt[c4 + k][rr * 16 + r] = __float2bfloat16(v[k]);
  }
  __syncthreads();
  const int a = t >> 2;
  const int b16 = (t & 3) * 16;
  ushort8* dp = (ushort8*)(dst + (size_t)(tj * 64 + a) * 2048 + ti * 64 + b16);
  const unsigned short* lp = (const unsigned short*)&lt[a][b16];
  ushort8 o0, o1;
#pragma unroll
  for (int k = 0; k < 8; ++k) {
    o0[k] = lp[k];
    o1[k] = lp[8 + k];
  }
  dp[0] = o0;
  dp[1] = o1;
}

// weights only: Wq/Wk/Wv transpose-cast (1024 blocks each) + Wo plain (2048)
__global__ __launch_bounds__(256) void cast_w(
    const float* __restrict__ wq, const float* __restrict__ wk,
    const float* __restrict__ wv, const float* __restrict__ wo,
    __hip_bfloat16* __restrict__ wqt, __hip_bfloat16* __restrict__ wkt,
    __hip_bfloat16* __restrict__ wvt, __hip_bfloat16* __restrict__ wob) {
  const int b = blockIdx.x;
  if (b < 1024) { tcast64(wq, wqt, b); return; }
  if (b < 2048) { tcast64(wk, wkt, b - 1024); return; }
  if (b < 3072) { tcast64(wv, wvt, b - 2048); return; }
  const long i = ((long)(b - 3072) * 256 + threadIdx.x) * 8;
  const f32x4 a = *(const f32x4*)(wo + i);
  const f32x4 c = *(const f32x4*)(wo + i + 4);
  ushort8 o;
#pragma unroll
  for (int j = 0; j < 4; ++j) o[j] = f2bf(a[j]);
#pragma unroll
  for (int j = 0; j < 4; ++j) o[4 + j] = f2bf(c[j]);
  *(ushort8*)(wob + i) = o;
}

extern "C" void kernel_launch(void* const* d_in, const int* in_sizes, int n_in,
                              void* d_out, int out_size, void* d_ws,
                              size_t ws_size, hipStream_t stream) {
  (void)in_sizes; (void)n_in; (void)out_size; (void)ws_size;
  const float* x = (const float*)d_in[0];
  const float* Wq = (const float*)d_in[1];
  const float* Wk = (const float*)d_in[2];
  const float* Wv = (const float*)d_in[3];
  const float* Wo = (const float*)d_in[4];
  const float* bo = (const float*)d_in[5];
  float* out = (float*)d_out;

  const long MB = 1ll << 20;
  char* ws = (char*)d_ws;  // 370 MiB
  __hip_bfloat16* Xb  = (__hip_bfloat16*)(ws);             // 64 MiB
  __hip_bfloat16* xG  = (__hip_bfloat16*)(ws + 64 * MB);   // 64 MiB
  __hip_bfloat16* VOt = (__hip_bfloat16*)(ws + 128 * MB);  // 64 MiB
  __hip_bfloat16* WkT = (__hip_bfloat16*)(ws + 192 * MB);  // 8 MiB  [smallA y0]
  __hip_bfloat16* Wob = (__hip_bfloat16*)(ws + 200 * MB);  // 8 MiB  [smallA y1]
  __hip_bfloat16* WqT = (__hip_bfloat16*)(ws + 208 * MB);  // 8 MiB  [smallB y0]
  __hip_bfloat16* WvT = (__hip_bfloat16*)(ws + 216 * MB);  // 8 MiB  [smallB y1]
  __hip_bfloat16* Gt  = (__hip_bfloat16*)(ws + 224 * MB);  // 8 MiB  [smallC y0]
  __hip_bfloat16* Wvo = (__hip_bfloat16*)(ws + 232 * MB);  // 8 MiB  [smallC y1]
  char* LgP           = ws + 240 * MB;                     // 128 MiB (P bf16)
  float* PS           = (float*)(ws + 368 * MB);           // 1 MiB

  const long WSTRIDE = 8 * MB / 2;  // elements between y=0 / y=1 operands

  cast_w<<<dim3(5120), dim3(256), 0, stream>>>(Wq, Wk, Wv, Wo, WqT, WkT, WvT,
                                               Wob);
  g_small_x<<<dim3(2112, 2), dim3(512), 0, stream>>>(WkT, WqT, Gt, WSTRIDE, x,
                                                     Xb);
  g_xgvot<<<dim3(256, 1), dim3(512), 0, stream>>>(Xb, Gt, xG, Wvo, VOt);
  g_qkt<<<dim3(64, NB_), dim3(512), 0, stream>>>(
      xG, Xb, (__hip_bfloat16*)LgP, PS);
  g_pv<<<dim3(64, NB_), dim3(512), 0, stream>>>(
      (const __hip_bfloat16*)LgP, VOt, out, bo, PS);
}